// Round 8
// baseline (823.099 us; speedup 1.0000x reference)
//
#include <hip/hip_runtime.h>
#include <math.h>

#define M_ROWS 2048
#define N_COLS 2048
#define DIMS 512
#define IN_STRIDE 513
#define DP_BLOCKS 32
#define DP_COLS 64
#define BAND 16

constexpr float GAMMA = 0.001f;
constexpr float LOG2E = 1.44269504088896f;
constexpr float LN2   = 0.69314718055995f;

__device__ __forceinline__ float fexp2(float x) { return __builtin_amdgcn_exp2f(x); }
__device__ __forceinline__ float flog2(float x) { return __builtin_amdgcn_logf(x); }

// ---------------- argsort by timestamp (last column), stable ----------------
__global__ void argsort_kernel(const float* __restrict__ a, const float* __restrict__ b,
                               int* __restrict__ permA, int* __restrict__ permB) {
    const float* src = blockIdx.y ? b : a;
    int* perm = blockIdx.y ? permB : permA;
    __shared__ float keys[M_ROWS];
    for (int j = threadIdx.x; j < M_ROWS; j += blockDim.x)
        keys[j] = src[(size_t)j * IN_STRIDE + DIMS];
    __syncthreads();
    int i = blockIdx.x * blockDim.x + threadIdx.x;
    float ki = keys[i];
    int rank = 0;
    for (int j = 0; j < M_ROWS; ++j) {
        float kj = keys[j];
        rank += (kj < ki) || (kj == ki && j < i);
    }
    perm[rank] = i;
}

// ---------------- gather sorted rows + L2-normalize (drop time col) ----------------
__global__ __launch_bounds__(128) void norm_kernel(const float* __restrict__ a, const float* __restrict__ b,
                                                   const int* __restrict__ permA, const int* __restrict__ permB,
                                                   float* __restrict__ Ahat, float* __restrict__ Bhat) {
    const float* src = blockIdx.y ? b : a;
    const int* perm = blockIdx.y ? permB : permA;
    float* dst = blockIdx.y ? Bhat : Ahat;
    int r = blockIdx.x;
    int row = perm[r];
    const float* p = src + (size_t)row * IN_STRIDE;
    int tid = threadIdx.x;
    float v0 = p[tid], v1 = p[tid + 128], v2 = p[tid + 256], v3 = p[tid + 384];
    float ss = v0 * v0 + v1 * v1 + v2 * v2 + v3 * v3;
    #pragma unroll
    for (int off = 32; off > 0; off >>= 1) ss += __shfl_down(ss, off);
    __shared__ float red[2];
    if ((tid & 63) == 0) red[tid >> 6] = ss;
    __syncthreads();
    float inv = 1.0f / sqrtf(red[0] + red[1] + 1e-10f);
    float* q = dst + (size_t)r * DIMS;
    q[tid] = v0 * inv; q[tid + 128] = v1 * inv; q[tid + 256] = v2 * inv; q[tid + 384] = v3 * inv;
}

// ---------------- GEMM: Q[i][n] = exp(-1 - dot(Ahat[i], Bhat[n])) ----------------
__global__ __launch_bounds__(256) void gemm_kernel(const float* __restrict__ A, const float* __restrict__ B,
                                                   float* __restrict__ Q) {
    __shared__ float As[16][68];
    __shared__ float Bs[16][68];
    int tid = threadIdx.x;
    int tx = tid & 15, ty = tid >> 4;
    int row0 = blockIdx.y * 64;
    int col0 = blockIdx.x * 64;
    int lrow = tid >> 2;
    int lk = (tid & 3) * 4;
    const float* ap = A + (size_t)(row0 + lrow) * DIMS + lk;
    const float* bp = B + (size_t)(col0 + lrow) * DIMS + lk;
    float acc[4][4] = {};
    for (int k0 = 0; k0 < DIMS; k0 += 16) {
        float4 av = *(const float4*)ap; ap += 16;
        float4 bv = *(const float4*)bp; bp += 16;
        __syncthreads();
        As[lk + 0][lrow] = av.x; As[lk + 1][lrow] = av.y; As[lk + 2][lrow] = av.z; As[lk + 3][lrow] = av.w;
        Bs[lk + 0][lrow] = bv.x; Bs[lk + 1][lrow] = bv.y; Bs[lk + 2][lrow] = bv.z; Bs[lk + 3][lrow] = bv.w;
        __syncthreads();
        #pragma unroll
        for (int k = 0; k < 16; ++k) {
            float4 a4 = *(const float4*)&As[k][ty * 4];
            float4 b4 = *(const float4*)&Bs[k][tx * 4];
            float aa[4] = {a4.x, a4.y, a4.z, a4.w};
            float bb[4] = {b4.x, b4.y, b4.z, b4.w};
            #pragma unroll
            for (int u = 0; u < 4; ++u)
                #pragma unroll
                for (int v = 0; v < 4; ++v)
                    acc[u][v] += aa[u] * bb[v];
        }
    }
    #pragma unroll
    for (int u = 0; u < 4; ++u) {
        float4 o;
        o.x = __expf(-1.0f - acc[u][0]);
        o.y = __expf(-1.0f - acc[u][1]);
        o.z = __expf(-1.0f - acc[u][2]);
        o.w = __expf(-1.0f - acc[u][3]);
        *(float4*)&Q[(size_t)(row0 + ty * 4 + u) * N_COLS + col0 + tx * 4] = o;
    }
}

// ------- per-row softmax denom -> rs = log2e/(gamma*denom); also Ew = 2^-rs -------
__global__ __launch_bounds__(256) void rowstat_kernel(const float* __restrict__ Q,
                                                      float* __restrict__ rowscale,
                                                      float* __restrict__ ews) {
    int i = blockIdx.x;
    const float* q = Q + (size_t)i * N_COLS;
    int tid = threadIdx.x;
    float4 x = *(const float4*)(q + tid * 4);
    float4 y = *(const float4*)(q + 1024 + tid * 4);
    float s = x.x + x.y + x.z + x.w + y.x + y.y + y.z + y.w;
    #pragma unroll
    for (int off = 32; off > 0; off >>= 1) s += __shfl_down(s, off);
    __shared__ float red[4];
    if ((tid & 63) == 0) red[tid >> 6] = s;
    __syncthreads();
    if (tid == 0) {
        float denom = 2049.0f + red[0] + red[1] + red[2] + red[3];
        float rs = (LOG2E / GAMMA) / denom;
        rowscale[i] = rs;
        ews[i] = fexp2(-rs);
    }
}

// ---- ELT[col][row] = 2^-rs + 2^(-rs*Q[row][col])  (LINEAR weight), transposed ----
__global__ __launch_bounds__(256) void lgt_kernel(const float* __restrict__ Q,
                                                  const float* __restrict__ rowscale,
                                                  float* __restrict__ ELT) {
    __shared__ float tile[64][65];
    const int row0 = blockIdx.y * 64;
    const int col0 = blockIdx.x * 64;
    const int t = threadIdx.x;
    const int c4 = (t & 15) * 4;
    const int r  = t >> 4;           // 0..15
    #pragma unroll
    for (int rr = 0; rr < 64; rr += 16) {
        int row = row0 + rr + r;
        float rs = rowscale[row];
        float4 v = *(const float4*)(Q + (size_t)row * N_COLS + col0 + c4);
        float e = fexp2(-rs);
        tile[c4 + 0][rr + r] = e + fexp2(-rs * v.x);
        tile[c4 + 1][rr + r] = e + fexp2(-rs * v.y);
        tile[c4 + 2][rr + r] = e + fexp2(-rs * v.z);
        tile[c4 + 3][rr + r] = e + fexp2(-rs * v.w);
    }
    __syncthreads();
    #pragma unroll
    for (int cc = 0; cc < 64; cc += 16) {
        int col = cc + r;
        float4 o;
        o.x = tile[col][c4 + 0];
        o.y = tile[col][c4 + 1];
        o.z = tile[col][c4 + 2];
        o.w = tile[col][c4 + 3];
        *(float4*)(ELT + (size_t)(col0 + col) * M_ROWS + row0 + c4) = o;
    }
}

// Hard materialization point: forces v into a VGPR here (and keeps it there),
// preventing the compiler from sinking the feeding load into the row bodies.
#define KEEP4(v) asm volatile("" : "+v"(v.x), "+v"(v.y), "+v"(v.z), "+v"(v.w))

// ---------------- single-instruction DPP scan stage ----------------
// v_add_f32_dpp: dst = dpp(src0) + src1 -> t = shifted(t) + t, ONE chained op
// per stage.  s_nop 1 gives the 2 wait states for the VALU-write->DPP-read
// software hazard.  bound_ctrl:0 => out-of-range source lanes contribute 0.
#define SST(V, MODS) asm("s_nop 1\n\tv_add_f32_dpp %0, %0, %0 " MODS : "+v"(V))
#define SCAN6                                                            \
    SST(t, "row_shr:1 row_mask:0xf bank_mask:0xf bound_ctrl:0");         \
    SST(t, "row_shr:2 row_mask:0xf bank_mask:0xf bound_ctrl:0");         \
    SST(t, "row_shr:4 row_mask:0xf bank_mask:0xf bound_ctrl:0");         \
    SST(t, "row_shr:8 row_mask:0xf bank_mask:0xf bound_ctrl:0");         \
    SST(t, "row_bcast:15 row_mask:0xa bank_mask:0xf bound_ctrl:0");      \
    SST(t, "row_bcast:31 row_mask:0xc bank_mask:0xf bound_ctrl:0")

// ---------------- linear-space row body ----------------
// State: wave-uniform exponent Rm (renormed every 8 rows) + per-lane mantissa
// w[n] = 2^(V[n]-Rm).  Row update (exact re-association):
//   w_new[n] = ci + sum_{k<n} w[k]*EL[k] + w[n]*Ew
//            = (ci + w*(Ew-EL)) + incl_scan(w*EL)[n]
// 'pre' uses only pre-scan values -> issues during the scan; post-scan tail is
// one add.  ci comes from vci (carry mantissa * 2^(producer_Rm - Rm)),
// pre-scaled once per 4-row group in WAIT_GROUP.
#define DP_ROW(U, ELV, EWV)                                                      \
    {                                                                            \
        float ci = 0.f;                                                          \
        if (s > 0)                                                               \
            ci = __int_as_float(__builtin_amdgcn_readlane(                       \
                     __float_as_int(vci), (U)));                                 \
        float t = w * (ELV);                                                     \
        float pre = fmaf(w, (EWV) - (ELV), ci);                                  \
        SCAN6;                                                                   \
        float all = ci + t;                                                      \
        float wn = pre + t;                                                      \
        if (s < DP_BLOCKS - 1) {                                                 \
            if (lane == 63) {                                                    \
                unsigned long long po =                                          \
                    ((unsigned long long)__float_as_uint(all) << 32)             \
                    | (unsigned long long)__float_as_uint(Rm);                   \
                __hip_atomic_store(pub + base + (U), po, __ATOMIC_RELAXED,       \
                                   __HIP_MEMORY_SCOPE_AGENT);                    \
            }                                                                    \
        } else {                                                                 \
            h = fmaf(h, (EWV), all);                                             \
        }                                                                        \
        w = wn;                                                                  \
    }

// Renorm the shared exponent from lane 48's mantissa, every 8 rows.
#define RENORM8                                                                  \
    {                                                                            \
        int e48 = __builtin_amdgcn_readlane(__builtin_amdgcn_frexp_expf(w), 48); \
        float f = __int_as_float((127 - e48) << 23);                             \
        w *= f; h *= f;                                                          \
        Rm += (float)e48;                                                        \
    }

// Wait for the 4-row group we are about to consume; refresh stale flags of this
// and later groups while spinning.  vci = carry mantissas scaled into our frame.
#define WAIT_GROUP(g)                                                            \
    if (s > 0) {                                                                 \
        for (;;) {                                                               \
            unsigned long long miss =                                            \
                __ballot(((lane >> 2) == (g)) && pk == 0ull);                    \
            if (miss == 0ull) break;                                             \
            if (pk == 0ull && (lane >> 2) >= (g))                                \
                pk = __hip_atomic_load(sub + base + lane, __ATOMIC_RELAXED,      \
                                       __HIP_MEMORY_SCOPE_AGENT);               \
        }                                                                        \
        int pkLo = (int)(unsigned)(pk & 0xFFFFFFFFull);                          \
        int pkHi = (int)(unsigned)(pk >> 32);                                    \
        float cf = fexp2(                                                        \
            __int_as_float(__builtin_amdgcn_readlane(pkLo, 4 * (g))) - Rm);      \
        vci = __int_as_float(pkHi) * cf;                                         \
    }

// Mid-group speculative re-poll for the NEXT group's carries: issued ~480 cy
// before its WAIT, when the producer (one group ahead) has usually published.
// One shot only — the pk==0 test forces completion of any prior outstanding
// pk load, so chaining shots would inject vmcnt stalls into the compute.
#define REFRESH(gn)                                                              \
    if (s > 0 && pk == 0ull && (lane >> 2) == (gn))                              \
        pk = __hip_atomic_load(sub + base + lane, __ATOMIC_RELAXED,              \
                               __HIP_MEMORY_SCOPE_AGENT);

__global__ __launch_bounds__(64) void dp_kernel(const float* __restrict__ ELT,
                                                const float* __restrict__ Ews,
                                                unsigned long long* __restrict__ carry,
                                                float* __restrict__ out) {
    const int s = ((blockIdx.x & 7) << 2) | (blockIdx.x >> 3);  // XCD-aware stripe id
    const int lane = threadIdx.x;
    const float* lcol = ELT + (size_t)(s * DP_COLS + lane) * M_ROWS;
    unsigned long long* pub = carry + (size_t)s * M_ROWS;
    const unsigned long long* sub = carry + (size_t)(s - 1) * M_ROWS;

    float w = 1.f;                 // virtual row -1: V = 0 for every column
    float Rm = 0.f;                // shared exponent
    float h = 1.f;                 // head accumulator (stripe 31, lane 63)
    float vci = 0.f;

    float4 lq0 = *(const float4*)(lcol + 0);
    float4 lq1 = *(const float4*)(lcol + 4);
    float4 lq2 = *(const float4*)(lcol + 8);
    float4 lq3 = *(const float4*)(lcol + 12);
    float4 ev0 = *(const float4*)(Ews + 0);
    float4 ev1 = *(const float4*)(Ews + 4);
    float4 ev2 = *(const float4*)(Ews + 8);
    float4 ev3 = *(const float4*)(Ews + 12);
    KEEP4(lq0); KEEP4(lq1); KEEP4(lq2); KEEP4(lq3);
    KEEP4(ev0); KEEP4(ev1); KEEP4(ev2); KEEP4(ev3);

    // speculative carry prefetch for band 0
    unsigned long long pk = 1ull;
    if (s > 0 && lane < BAND)
        pk = __hip_atomic_load(sub + lane, __ATOMIC_RELAXED, __HIP_MEMORY_SCOPE_AGENT);

    for (int base = 0; base < M_ROWS; base += BAND) {
        // prefetch next band's weights; KEEP4 pins them into VGPRs NOW so the
        // 16 rows below are register-only (one exposed load latency per band).
        float4 nl0{}, nl1{}, nl2{}, nl3{}, nv0{}, nv1{}, nv2{}, nv3{};
        if (base + BAND < M_ROWS) {
            nl0 = *(const float4*)(lcol + base + BAND);
            nl1 = *(const float4*)(lcol + base + BAND + 4);
            nl2 = *(const float4*)(lcol + base + BAND + 8);
            nl3 = *(const float4*)(lcol + base + BAND + 12);
            nv0 = *(const float4*)(Ews + base + BAND);
            nv1 = *(const float4*)(Ews + base + BAND + 4);
            nv2 = *(const float4*)(Ews + base + BAND + 8);
            nv3 = *(const float4*)(Ews + base + BAND + 12);
        }
        KEEP4(nl0); KEEP4(nl1); KEEP4(nl2); KEEP4(nl3);
        KEEP4(nv0); KEEP4(nv1); KEEP4(nv2); KEEP4(nv3);

        WAIT_GROUP(0)
        DP_ROW(0,  lq0.x, ev0.x)
        DP_ROW(1,  lq0.y, ev0.y)
        DP_ROW(2,  lq0.z, ev0.z)
        REFRESH(1)
        DP_ROW(3,  lq0.w, ev0.w)
        WAIT_GROUP(1)
        DP_ROW(4,  lq1.x, ev1.x)
        DP_ROW(5,  lq1.y, ev1.y)
        DP_ROW(6,  lq1.z, ev1.z)
        REFRESH(2)
        DP_ROW(7,  lq1.w, ev1.w)
        RENORM8
        WAIT_GROUP(2)
        DP_ROW(8,  lq2.x, ev2.x)
        DP_ROW(9,  lq2.y, ev2.y)
        DP_ROW(10, lq2.z, ev2.z)
        REFRESH(3)
        DP_ROW(11, lq2.w, ev2.w)
        WAIT_GROUP(3)
        // speculative carry load for the NEXT band (in flight during rows 12-15
        // and the next band's weight prefetch)
        {
            unsigned long long nk = 1ull;
            if (s > 0 && lane < BAND && base + BAND < M_ROWS)
                nk = __hip_atomic_load(sub + base + BAND + lane,
                                       __ATOMIC_RELAXED, __HIP_MEMORY_SCOPE_AGENT);
            DP_ROW(12, lq3.x, ev3.x)
            DP_ROW(13, lq3.y, ev3.y)
            DP_ROW(14, lq3.z, ev3.z)
            DP_ROW(15, lq3.w, ev3.w)
            RENORM8
            pk = nk;
        }

        lq0 = nl0; lq1 = nl1; lq2 = nl2; lq3 = nl3;
        ev0 = nv0; ev1 = nv1; ev2 = nv2; ev3 = nv3;
    }
    if (s == DP_BLOCKS - 1 && lane == 63)
        out[0] = -GAMMA * LN2 * (Rm + flog2(h));
}

extern "C" void kernel_launch(void* const* d_in, const int* in_sizes, int n_in,
                              void* d_out, int out_size, void* d_ws, size_t ws_size,
                              hipStream_t stream) {
    (void)in_sizes; (void)n_in; (void)out_size; (void)ws_size;
    const float* a = (const float*)d_in[0];
    const float* b = (const float*)d_in[1];
    float* out = (float*)d_out;
    char* ws = (char*)d_ws;
    float* Q        = (float*)(ws);                                    // 16 MB
    float* ELT      = (float*)(ws + (size_t)16 * 1024 * 1024);         // 16 MB
    float* Ahat     = (float*)(ws + (size_t)32 * 1024 * 1024);         // 4 MB
    float* Bhat     = (float*)(ws + (size_t)36 * 1024 * 1024);         // 4 MB
    float* rowscale = (float*)(ws + (size_t)40 * 1024 * 1024);         // 8 KB
    int* permA      = (int*)(ws + (size_t)40 * 1024 * 1024 + 8192);    // 8 KB
    int* permB      = (int*)(ws + (size_t)40 * 1024 * 1024 + 16384);   // 8 KB
    float* ews      = (float*)(ws + (size_t)40 * 1024 * 1024 + 24576); // 8 KB
    unsigned long long* carry = (unsigned long long*)(ws + (size_t)41 * 1024 * 1024); // 512 KB

    hipMemsetAsync(carry, 0, (size_t)DP_BLOCKS * M_ROWS * sizeof(unsigned long long), stream);
    argsort_kernel<<<dim3(8, 2), 256, 0, stream>>>(a, b, permA, permB);
    norm_kernel<<<dim3(2048, 2), 128, 0, stream>>>(a, b, permA, permB, Ahat, Bhat);
    gemm_kernel<<<dim3(32, 32), 256, 0, stream>>>(Ahat, Bhat, Q);
    rowstat_kernel<<<2048, 256, 0, stream>>>(Q, rowscale, ews);
    lgt_kernel<<<dim3(32, 32), 256, 0, stream>>>(Q, rowscale, ELT);
    dp_kernel<<<DP_BLOCKS, DP_COLS, 0, stream>>>(ELT, ews, carry, out);
}

// Round 10
// 574.741 us; speedup vs baseline: 1.4321x; 1.4321x over previous
//
#include <hip/hip_runtime.h>
#include <math.h>

#define M_ROWS 2048
#define N_COLS 2048
#define DIMS 512
#define IN_STRIDE 513
#define DP_BLOCKS 32
#define DP_COLS 64
#define BAND 16

constexpr float GAMMA = 0.001f;
constexpr float LOG2E = 1.44269504088896f;
constexpr float LN2   = 0.69314718055995f;

__device__ __forceinline__ float fexp2(float x) { return __builtin_amdgcn_exp2f(x); }
__device__ __forceinline__ float flog2(float x) { return __builtin_amdgcn_logf(x); }

// ---------------- argsort by timestamp (last column), stable ----------------
__global__ void argsort_kernel(const float* __restrict__ a, const float* __restrict__ b,
                               int* __restrict__ permA, int* __restrict__ permB) {
    const float* src = blockIdx.y ? b : a;
    int* perm = blockIdx.y ? permB : permA;
    __shared__ float keys[M_ROWS];
    for (int j = threadIdx.x; j < M_ROWS; j += blockDim.x)
        keys[j] = src[(size_t)j * IN_STRIDE + DIMS];
    __syncthreads();
    int i = blockIdx.x * blockDim.x + threadIdx.x;
    float ki = keys[i];
    int rank = 0;
    for (int j = 0; j < M_ROWS; ++j) {
        float kj = keys[j];
        rank += (kj < ki) || (kj == ki && j < i);
    }
    perm[rank] = i;
}

// ---------------- gather sorted rows + L2-normalize (drop time col) ----------------
__global__ __launch_bounds__(128) void norm_kernel(const float* __restrict__ a, const float* __restrict__ b,
                                                   const int* __restrict__ permA, const int* __restrict__ permB,
                                                   float* __restrict__ Ahat, float* __restrict__ Bhat) {
    const float* src = blockIdx.y ? b : a;
    const int* perm = blockIdx.y ? permB : permA;
    float* dst = blockIdx.y ? Bhat : Ahat;
    int r = blockIdx.x;
    int row = perm[r];
    const float* p = src + (size_t)row * IN_STRIDE;
    int tid = threadIdx.x;
    float v0 = p[tid], v1 = p[tid + 128], v2 = p[tid + 256], v3 = p[tid + 384];
    float ss = v0 * v0 + v1 * v1 + v2 * v2 + v3 * v3;
    #pragma unroll
    for (int off = 32; off > 0; off >>= 1) ss += __shfl_down(ss, off);
    __shared__ float red[2];
    if ((tid & 63) == 0) red[tid >> 6] = ss;
    __syncthreads();
    float inv = 1.0f / sqrtf(red[0] + red[1] + 1e-10f);
    float* q = dst + (size_t)r * DIMS;
    q[tid] = v0 * inv; q[tid + 128] = v1 * inv; q[tid + 256] = v2 * inv; q[tid + 384] = v3 * inv;
}

// ---------------- GEMM: Q[i][n] = exp(-1 - dot(Ahat[i], Bhat[n])) ----------------
__global__ __launch_bounds__(256) void gemm_kernel(const float* __restrict__ A, const float* __restrict__ B,
                                                   float* __restrict__ Q) {
    __shared__ float As[16][68];
    __shared__ float Bs[16][68];
    int tid = threadIdx.x;
    int tx = tid & 15, ty = tid >> 4;
    int row0 = blockIdx.y * 64;
    int col0 = blockIdx.x * 64;
    int lrow = tid >> 2;
    int lk = (tid & 3) * 4;
    const float* ap = A + (size_t)(row0 + lrow) * DIMS + lk;
    const float* bp = B + (size_t)(col0 + lrow) * DIMS + lk;
    float acc[4][4] = {};
    for (int k0 = 0; k0 < DIMS; k0 += 16) {
        float4 av = *(const float4*)ap; ap += 16;
        float4 bv = *(const float4*)bp; bp += 16;
        __syncthreads();
        As[lk + 0][lrow] = av.x; As[lk + 1][lrow] = av.y; As[lk + 2][lrow] = av.z; As[lk + 3][lrow] = av.w;
        Bs[lk + 0][lrow] = bv.x; Bs[lk + 1][lrow] = bv.y; Bs[lk + 2][lrow] = bv.z; Bs[lk + 3][lrow] = bv.w;
        __syncthreads();
        #pragma unroll
        for (int k = 0; k < 16; ++k) {
            float4 a4 = *(const float4*)&As[k][ty * 4];
            float4 b4 = *(const float4*)&Bs[k][tx * 4];
            float aa[4] = {a4.x, a4.y, a4.z, a4.w};
            float bb[4] = {b4.x, b4.y, b4.z, b4.w};
            #pragma unroll
            for (int u = 0; u < 4; ++u)
                #pragma unroll
                for (int v = 0; v < 4; ++v)
                    acc[u][v] += aa[u] * bb[v];
        }
    }
    #pragma unroll
    for (int u = 0; u < 4; ++u) {
        float4 o;
        o.x = __expf(-1.0f - acc[u][0]);
        o.y = __expf(-1.0f - acc[u][1]);
        o.z = __expf(-1.0f - acc[u][2]);
        o.w = __expf(-1.0f - acc[u][3]);
        *(float4*)&Q[(size_t)(row0 + ty * 4 + u) * N_COLS + col0 + tx * 4] = o;
    }
}

// ------- per-row softmax denom -> rs = log2e/(gamma*denom); also Ew = 2^-rs -------
__global__ __launch_bounds__(256) void rowstat_kernel(const float* __restrict__ Q,
                                                      float* __restrict__ rowscale,
                                                      float* __restrict__ ews) {
    int i = blockIdx.x;
    const float* q = Q + (size_t)i * N_COLS;
    int tid = threadIdx.x;
    float4 x = *(const float4*)(q + tid * 4);
    float4 y = *(const float4*)(q + 1024 + tid * 4);
    float s = x.x + x.y + x.z + x.w + y.x + y.y + y.z + y.w;
    #pragma unroll
    for (int off = 32; off > 0; off >>= 1) s += __shfl_down(s, off);
    __shared__ float red[4];
    if ((tid & 63) == 0) red[tid >> 6] = s;
    __syncthreads();
    if (tid == 0) {
        float denom = 2049.0f + red[0] + red[1] + red[2] + red[3];
        float rs = (LOG2E / GAMMA) / denom;
        rowscale[i] = rs;
        ews[i] = fexp2(-rs);
    }
}

// ---- ELT[col][row] = 2^-rs + 2^(-rs*Q[row][col])  (LINEAR weight), transposed ----
__global__ __launch_bounds__(256) void lgt_kernel(const float* __restrict__ Q,
                                                  const float* __restrict__ rowscale,
                                                  float* __restrict__ ELT) {
    __shared__ float tile[64][65];
    const int row0 = blockIdx.y * 64;
    const int col0 = blockIdx.x * 64;
    const int t = threadIdx.x;
    const int c4 = (t & 15) * 4;
    const int r  = t >> 4;           // 0..15
    #pragma unroll
    for (int rr = 0; rr < 64; rr += 16) {
        int row = row0 + rr + r;
        float rs = rowscale[row];
        float4 v = *(const float4*)(Q + (size_t)row * N_COLS + col0 + c4);
        float e = fexp2(-rs);
        tile[c4 + 0][rr + r] = e + fexp2(-rs * v.x);
        tile[c4 + 1][rr + r] = e + fexp2(-rs * v.y);
        tile[c4 + 2][rr + r] = e + fexp2(-rs * v.z);
        tile[c4 + 3][rr + r] = e + fexp2(-rs * v.w);
    }
    __syncthreads();
    #pragma unroll
    for (int cc = 0; cc < 64; cc += 16) {
        int col = cc + r;
        float4 o;
        o.x = tile[col][c4 + 0];
        o.y = tile[col][c4 + 1];
        o.z = tile[col][c4 + 2];
        o.w = tile[col][c4 + 3];
        *(float4*)(ELT + (size_t)(col0 + col) * M_ROWS + row0 + c4) = o;
    }
}

// Hard materialization point: forces v into a VGPR here (and keeps it there),
// preventing the compiler from sinking the feeding load into the row bodies.
#define KEEP4(v) asm volatile("" : "+v"(v.x), "+v"(v.y), "+v"(v.z), "+v"(v.w))

// ---------------- single-instruction DPP scan stage (round-5-proven) ----------------
#define SST(V, MODS) asm("s_nop 1\n\tv_add_f32_dpp %0, %0, %0 " MODS : "+v"(V))
#define SCAN6                                                            \
    SST(t, "row_shr:1 row_mask:0xf bank_mask:0xf bound_ctrl:0");         \
    SST(t, "row_shr:2 row_mask:0xf bank_mask:0xf bound_ctrl:0");         \
    SST(t, "row_shr:4 row_mask:0xf bank_mask:0xf bound_ctrl:0");         \
    SST(t, "row_shr:8 row_mask:0xf bank_mask:0xf bound_ctrl:0");         \
    SST(t, "row_bcast:15 row_mask:0xa bank_mask:0xf bound_ctrl:0");      \
    SST(t, "row_bcast:31 row_mask:0xc bank_mask:0xf bound_ctrl:0")

// ---------------- linear-space row body (verbatim round 5) ----------------
// w_new[n] = ci + sum_{k<n} w[k]*EL[k] + w[n]*Ew
//          = (ci + w*(Ew-EL)) + incl_scan(w*EL)[n]
// ci comes from VCI (carry mantissa * 2^(producer_Rm - consumer_Rm)); VCI is
// computed once per 8-row half-band (producer Rm is constant per half, since
// the producer renorms only at rows 7/15 of its bands).
#define DP_ROW(U, ELV, EWV, VCI)                                                 \
    {                                                                            \
        float ci = 0.f;                                                          \
        if (s > 0)                                                               \
            ci = __int_as_float(__builtin_amdgcn_readlane(                       \
                     __float_as_int(VCI), (U)));                                 \
        float t = w * (ELV);                                                     \
        float pre = fmaf(w, (EWV) - (ELV), ci);                                  \
        SCAN6;                                                                   \
        float all = ci + t;                                                      \
        float wn = pre + t;                                                      \
        if (s < DP_BLOCKS - 1) {                                                 \
            if (lane == 63) {                                                    \
                unsigned long long po =                                          \
                    ((unsigned long long)__float_as_uint(all) << 32)             \
                    | (unsigned long long)__float_as_uint(Rm);                   \
                __hip_atomic_store(pub + base + (U), po, __ATOMIC_RELAXED,       \
                                   __HIP_MEMORY_SCOPE_AGENT);                    \
            }                                                                    \
        } else {                                                                 \
            h = fmaf(h, (EWV), all);                                             \
        }                                                                        \
        w = wn;                                                                  \
    }

// Renorm the shared exponent from lane 48's mantissa, every 8 rows.
#define RENORM8                                                                  \
    {                                                                            \
        int e48 = __builtin_amdgcn_readlane(__builtin_amdgcn_frexp_expf(w), 48); \
        float f = __int_as_float((127 - e48) << 23);                             \
        w *= f; h *= f;                                                          \
        Rm += (float)e48;                                                        \
    }

// Band-granular wait (round-0-proven spin): one wait per 16 rows amortizes the
// ~660-cycle carry-observation round trip 4x better than per-4-row waits
// (round-8 measured the round-trip cost directly: +165 cy/row for one extra
// load+consume per group).
#define WAIT_BAND                                                                \
    if (s > 0) {                                                                 \
        for (;;) {                                                               \
            unsigned long long miss = __ballot((lane < BAND) && pk == 0ull);     \
            if (miss == 0ull) break;                                             \
            if (pk == 0ull && lane < BAND)                                       \
                pk = __hip_atomic_load(sub + base + lane, __ATOMIC_RELAXED,      \
                                       __HIP_MEMORY_SCOPE_AGENT);               \
        }                                                                        \
        pkLo = (int)(unsigned)(pk & 0xFFFFFFFFull);                              \
        pkHi = (int)(unsigned)(pk >> 32);                                        \
    }

__global__ __launch_bounds__(64) void dp_kernel(const float* __restrict__ ELT,
                                                const float* __restrict__ Ews,
                                                unsigned long long* __restrict__ carry,
                                                float* __restrict__ out) {
    const int s = ((blockIdx.x & 7) << 2) | (blockIdx.x >> 3);  // XCD-aware stripe id
    const int lane = threadIdx.x;
    const float* lcol = ELT + (size_t)(s * DP_COLS + lane) * M_ROWS;
    unsigned long long* pub = carry + (size_t)s * M_ROWS;
    const unsigned long long* sub = carry + (size_t)(s - 1) * M_ROWS;

    float w = 1.f;                 // virtual row -1: V = 0 for every column
    float Rm = 0.f;                // shared exponent
    float h = 1.f;                 // head accumulator (stripe 31, lane 63)

    float4 lq0 = *(const float4*)(lcol + 0);
    float4 lq1 = *(const float4*)(lcol + 4);
    float4 lq2 = *(const float4*)(lcol + 8);
    float4 lq3 = *(const float4*)(lcol + 12);
    float4 ev0 = *(const float4*)(Ews + 0);
    float4 ev1 = *(const float4*)(Ews + 4);
    float4 ev2 = *(const float4*)(Ews + 8);
    float4 ev3 = *(const float4*)(Ews + 12);
    KEEP4(lq0); KEEP4(lq1); KEEP4(lq2); KEEP4(lq3);
    KEEP4(ev0); KEEP4(ev1); KEEP4(ev2); KEEP4(ev3);

    // speculative carry prefetch for band 0
    unsigned long long pk = 1ull;
    if (s > 0 && lane < BAND)
        pk = __hip_atomic_load(sub + lane, __ATOMIC_RELAXED, __HIP_MEMORY_SCOPE_AGENT);

    for (int base = 0; base < M_ROWS; base += BAND) {
        // prefetch next band's weights; KEEP4 pins them into VGPRs NOW so the
        // 16 rows below are register-only (one exposed load latency per band).
        float4 nl0{}, nl1{}, nl2{}, nl3{}, nv0{}, nv1{}, nv2{}, nv3{};
        if (base + BAND < M_ROWS) {
            nl0 = *(const float4*)(lcol + base + BAND);
            nl1 = *(const float4*)(lcol + base + BAND + 4);
            nl2 = *(const float4*)(lcol + base + BAND + 8);
            nl3 = *(const float4*)(lcol + base + BAND + 12);
            nv0 = *(const float4*)(Ews + base + BAND);
            nv1 = *(const float4*)(Ews + base + BAND + 4);
            nv2 = *(const float4*)(Ews + base + BAND + 8);
            nv3 = *(const float4*)(Ews + base + BAND + 12);
        }
        KEEP4(nl0); KEEP4(nl1); KEEP4(nl2); KEEP4(nl3);
        KEEP4(nv0); KEEP4(nv1); KEEP4(nv2); KEEP4(nv3);

        int pkLo = 0, pkHi = 0;
        WAIT_BAND
        // carry pre-scale for rows 0-7 (producer Rm constant over the half-band)
        float vci01 = 0.f;
        if (s > 0)
            vci01 = __int_as_float(pkHi) * fexp2(
                __int_as_float(__builtin_amdgcn_readlane(pkLo, 0)) - Rm);

        DP_ROW(0,  lq0.x, ev0.x, vci01)
        DP_ROW(1,  lq0.y, ev0.y, vci01)
        DP_ROW(2,  lq0.z, ev0.z, vci01)
        DP_ROW(3,  lq0.w, ev0.w, vci01)
        DP_ROW(4,  lq1.x, ev1.x, vci01)
        DP_ROW(5,  lq1.y, ev1.y, vci01)
        DP_ROW(6,  lq1.z, ev1.z, vci01)
        DP_ROW(7,  lq1.w, ev1.w, vci01)
        RENORM8
        // carry pre-scale for rows 8-15, in the POST-renorm Rm frame
        float vci23 = 0.f;
        if (s > 0)
            vci23 = __int_as_float(pkHi) * fexp2(
                __int_as_float(__builtin_amdgcn_readlane(pkLo, 8)) - Rm);
        // speculative carry load for the NEXT band (~8-row lead: the producer,
        // one band ahead, has published roughly half of it; the band-wait spin
        // mops up the rest with ~1 round trip per band)
        unsigned long long nk = 1ull;
        if (s > 0 && lane < BAND && base + BAND < M_ROWS)
            nk = __hip_atomic_load(sub + base + BAND + lane,
                                   __ATOMIC_RELAXED, __HIP_MEMORY_SCOPE_AGENT);

        DP_ROW(8,  lq2.x, ev2.x, vci23)
        DP_ROW(9,  lq2.y, ev2.y, vci23)
        DP_ROW(10, lq2.z, ev2.z, vci23)
        DP_ROW(11, lq2.w, ev2.w, vci23)
        DP_ROW(12, lq3.x, ev3.x, vci23)
        DP_ROW(13, lq3.y, ev3.y, vci23)
        DP_ROW(14, lq3.z, ev3.z, vci23)
        DP_ROW(15, lq3.w, ev3.w, vci23)
        RENORM8
        pk = nk;

        lq0 = nl0; lq1 = nl1; lq2 = nl2; lq3 = nl3;
        ev0 = nv0; ev1 = nv1; ev2 = nv2; ev3 = nv3;
    }
    if (s == DP_BLOCKS - 1 && lane == 63)
        out[0] = -GAMMA * LN2 * (Rm + flog2(h));
}

extern "C" void kernel_launch(void* const* d_in, const int* in_sizes, int n_in,
                              void* d_out, int out_size, void* d_ws, size_t ws_size,
                              hipStream_t stream) {
    (void)in_sizes; (void)n_in; (void)out_size; (void)ws_size;
    const float* a = (const float*)d_in[0];
    const float* b = (const float*)d_in[1];
    float* out = (float*)d_out;
    char* ws = (char*)d_ws;
    float* Q        = (float*)(ws);                                    // 16 MB
    float* ELT      = (float*)(ws + (size_t)16 * 1024 * 1024);         // 16 MB
    float* Ahat     = (float*)(ws + (size_t)32 * 1024 * 1024);         // 4 MB
    float* Bhat     = (float*)(ws + (size_t)36 * 1024 * 1024);         // 4 MB
    float* rowscale = (float*)(ws + (size_t)40 * 1024 * 1024);         // 8 KB
    int* permA      = (int*)(ws + (size_t)40 * 1024 * 1024 + 8192);    // 8 KB
    int* permB      = (int*)(ws + (size_t)40 * 1024 * 1024 + 16384);   // 8 KB
    float* ews      = (float*)(ws + (size_t)40 * 1024 * 1024 + 24576); // 8 KB
    unsigned long long* carry = (unsigned long long*)(ws + (size_t)41 * 1024 * 1024); // 512 KB

    hipMemsetAsync(carry, 0, (size_t)DP_BLOCKS * M_ROWS * sizeof(unsigned long long), stream);
    argsort_kernel<<<dim3(8, 2), 256, 0, stream>>>(a, b, permA, permB);
    norm_kernel<<<dim3(2048, 2), 128, 0, stream>>>(a, b, permA, permB, Ahat, Bhat);
    gemm_kernel<<<dim3(32, 32), 256, 0, stream>>>(Ahat, Bhat, Q);
    rowstat_kernel<<<2048, 256, 0, stream>>>(Q, rowscale, ews);
    lgt_kernel<<<dim3(32, 32), 256, 0, stream>>>(Q, rowscale, ELT);
    dp_kernel<<<DP_BLOCKS, DP_COLS, 0, stream>>>(ELT, ews, carry, out);
}